// Round 3
// baseline (3557.362 us; speedup 1.0000x reference)
//
#include <hip/hip_runtime.h>
#include <cstdint>

static constexpr int N_NODES = 300000;
static constexpr int N_NETS  = 200000;
static constexpr int E_SINK  = 1000000;
static constexpr int NODE_DIM = 32;
static constexpr int NET_DIM  = 16;
static constexpr int EMB = 64;
static constexpr int NUM_VN = 1000;
#define SLOPE 0.01f

__device__ __forceinline__ float leaky(float x) { return x >= 0.f ? x : SLOPE * x; }
__device__ __forceinline__ float4 leaky4(float4 v) {
    return make_float4(leaky(v.x), leaky(v.y), leaky(v.z), leaky(v.w));
}

// order-preserving f32 -> u32 encoding for atomicMax
__device__ __forceinline__ unsigned enc(float x) {
    unsigned u = __float_as_uint(x);
    return (u & 0x80000000u) ? ~u : (u | 0x80000000u);
}
__device__ __forceinline__ float dec(unsigned e) {
    unsigned u = (e & 0x80000000u) ? (e ^ 0x80000000u) : ~e;
    return __uint_as_float(u);
}

// ============ weight transpose prep (into scratch; run before users) ========
// layout in scratch (floats):
//   [0)        ne_W1t  128x32   (=4096)
//   [4096)     te_W1t  64x16    (=1024)
//   [5120)     fc1n_Wt 256x64   (=16384)
//   [21504)    fc1e_Wt 64x64    (=4096)   total 25600
__global__ void k_prep_wt(const float* __restrict__ ne_W1, const float* __restrict__ te_W1,
                          const float* __restrict__ fc1n_W, const float* __restrict__ fc1e_W,
                          float* __restrict__ wt)
{
    int idx = blockIdx.x * blockDim.x + threadIdx.x;
    if (idx < 4096) {                       // ne: [32][128] -> [128][32]
        int m = idx >> 5, i = idx & 31;
        wt[idx] = ne_W1[i * 128 + m];
    } else if (idx < 5120) {                // te: [16][64] -> [64][16]
        int t = idx - 4096;
        int m = t >> 4, i = t & 15;
        wt[idx] = te_W1[i * 64 + m];
    } else if (idx < 21504) {               // fc1n: [64][256] -> [256][64]
        int t = idx - 5120;
        int r = t >> 6, k = t & 63;
        wt[idx] = fc1n_W[k * 256 + r];
    } else if (idx < 25600) {               // fc1e: [64][64] -> [64][64]
        int t = idx - 21504;
        int r = t >> 6, k = t & 63;
        wt[idx] = fc1e_W[k * 64 + r];
    }
}

// ================= encoders (thread-per-row, scalar weight loads) ==========

// node: 32 -> 128 (leaky) -> 64
__global__ __launch_bounds__(256) void k_node_enc(
    const float* __restrict__ x, const float* __restrict__ W1t, const float* __restrict__ b1,
    const float* __restrict__ W2, const float* __restrict__ b2, float* __restrict__ h)
{
    int nid = blockIdx.x * 256 + threadIdx.x;
    int n = min(nid, N_NODES - 1);

    float4 xr[8];
    const float4* xp = (const float4*)(x + (size_t)n * NODE_DIM);
#pragma unroll
    for (int q = 0; q < 8; ++q) xr[q] = xp[q];

    float4 a[16];
    const float4* b2p = (const float4*)b2;
#pragma unroll
    for (int q = 0; q < 16; ++q) a[q] = b2p[q];

#pragma unroll 1
    for (int m = 0; m < 128; ++m) {
        const float4* wr = (const float4*)(W1t + m * 32);
        float p0 = 0.f, p1 = 0.f, p2 = 0.f, p3 = 0.f;
#pragma unroll
        for (int q = 0; q < 8; ++q) {
            float4 v = wr[q];
            p0 += xr[q].x * v.x; p1 += xr[q].y * v.y;
            p2 += xr[q].z * v.z; p3 += xr[q].w * v.w;
        }
        float hm = leaky(b1[m] + ((p0 + p1) + (p2 + p3)));
        const float4* w2r = (const float4*)(W2 + m * 64);
#pragma unroll
        for (int q = 0; q < 16; ++q) {
            float4 v = w2r[q];
            a[q].x += hm * v.x; a[q].y += hm * v.y;
            a[q].z += hm * v.z; a[q].w += hm * v.w;
        }
    }
    if (nid < N_NODES) {
        float4* hp = (float4*)(h + (size_t)nid * EMB);
#pragma unroll
        for (int q = 0; q < 16; ++q) hp[q] = a[q];
    }
}

// net: 16 -> 64 (leaky) -> 64
__global__ __launch_bounds__(256) void k_net_enc(
    const float* __restrict__ x, const float* __restrict__ W1t, const float* __restrict__ b1,
    const float* __restrict__ W2, const float* __restrict__ b2, float* __restrict__ g)
{
    int nid = blockIdx.x * 256 + threadIdx.x;
    int n = min(nid, N_NETS - 1);

    float4 xr[4];
    const float4* xp = (const float4*)(x + (size_t)n * NET_DIM);
#pragma unroll
    for (int q = 0; q < 4; ++q) xr[q] = xp[q];

    float4 a[16];
    const float4* b2p = (const float4*)b2;
#pragma unroll
    for (int q = 0; q < 16; ++q) a[q] = b2p[q];

#pragma unroll 1
    for (int m = 0; m < 64; ++m) {
        const float4* wr = (const float4*)(W1t + m * 16);
        float p0 = 0.f, p1 = 0.f, p2 = 0.f, p3 = 0.f;
#pragma unroll
        for (int q = 0; q < 4; ++q) {
            float4 v = wr[q];
            p0 += xr[q].x * v.x; p1 += xr[q].y * v.y;
            p2 += xr[q].z * v.z; p3 += xr[q].w * v.w;
        }
        float hm = leaky(b1[m] + ((p0 + p1) + (p2 + p3)));
        const float4* w2r = (const float4*)(W2 + m * 64);
#pragma unroll
        for (int q = 0; q < 16; ++q) {
            float4 v = w2r[q];
            a[q].x += hm * v.x; a[q].y += hm * v.y;
            a[q].z += hm * v.z; a[q].w += hm * v.w;
        }
    }
    if (nid < N_NETS) {
        float4* gp = (float4*)(g + (size_t)nid * EMB);
#pragma unroll
        for (int q = 0; q < 16; ++q) gp[q] = a[q];
    }
}

// ================= misc elementwise =================
__global__ void k_vn_init(float* __restrict__ vn, const float* __restrict__ vn_emb) {
    int idx = blockIdx.x * blockDim.x + threadIdx.x;
    if (idx < NUM_VN * EMB) vn[idx] = vn_emb[idx & 63];
}

__global__ void k_add_vn(float4* __restrict__ h4, const float* __restrict__ vn,
                         const int* __restrict__ batch) {
    int idx = blockIdx.x * blockDim.x + threadIdx.x;
    if (idx >= N_NODES * 16) return;
    int n = idx >> 4, c4 = idx & 15;
    const float4* vr = (const float4*)(vn + (size_t)batch[n] * 64);
    float4 hv = h4[idx], vv = vr[c4];
    h4[idx] = make_float4(hv.x + vv.x, hv.y + vv.y, hv.z + vv.z, hv.w + vv.w);
}

__global__ void k_pool_init(unsigned* __restrict__ pooled) {
    int idx = blockIdx.x * blockDim.x + threadIdx.x;
    if (idx < NUM_VN * EMB) pooled[idx] = enc(-__builtin_inff());
}

// ================= scatters (wave per edge/row) =================
__global__ __launch_bounds__(256) void k_scatter_sink(
    float* __restrict__ agg, const float* __restrict__ h,
    const int* __restrict__ sink_nodes, const int* __restrict__ sink_nets,
    const float* __restrict__ ew)
{
    int wv = threadIdx.x >> 6, lane = threadIdx.x & 63;
    int e = blockIdx.x * 4 + wv;
    if (e >= E_SINK) return;
    int sn = sink_nodes[e], tg = sink_nets[e];
    float wt = ew[e];
    atomicAdd(&agg[(size_t)tg * 64 + lane], h[(size_t)sn * 64 + lane] * wt);
}

__global__ __launch_bounds__(256) void k_scatter_back_src(
    float* __restrict__ back, const float* __restrict__ g, const int* __restrict__ src_nodes)
{
    int wv = threadIdx.x >> 6, lane = threadIdx.x & 63;
    int n = blockIdx.x * 4 + wv;
    if (n >= N_NETS) return;
    atomicAdd(&back[(size_t)src_nodes[n] * 64 + lane], g[(size_t)n * 64 + lane]);
}

__global__ __launch_bounds__(256) void k_scatter_back_sink(
    float* __restrict__ back, const float* __restrict__ g,
    const int* __restrict__ sink_nets, const int* __restrict__ sink_nodes,
    const float* __restrict__ ew)
{
    int wv = threadIdx.x >> 6, lane = threadIdx.x & 63;
    int e = blockIdx.x * 4 + wv;
    if (e >= E_SINK) return;
    int tg = sink_nets[e], dn = sink_nodes[e];
    float wt = ew[e];
    atomicAdd(&back[(size_t)dn * 64 + lane], g[(size_t)tg * 64 + lane] * wt);
}

__global__ __launch_bounds__(256) void k_pool_scatter(
    unsigned* __restrict__ pooled, const float* __restrict__ h, const int* __restrict__ batch)
{
    int wv = threadIdx.x >> 6, lane = threadIdx.x & 63;
    int n = blockIdx.x * 4 + wv;
    if (n >= N_NODES) return;
    atomicMax(&pooled[batch[n] * 64 + lane], enc(h[(size_t)n * 64 + lane]));
}

// ================= conv layers (thread-per-row, scalar weight loads) ========

__device__ __forceinline__ void acc_part(float4 a[16], const float4 in[16],
                                         const float* __restrict__ Wp)
{
#pragma unroll 1
    for (int k4 = 0; k4 < 16; ++k4) {
        float4 iv = in[k4];
        const float4* w0 = (const float4*)(Wp + (k4 * 4 + 0) * 64);
        const float4* w1 = (const float4*)(Wp + (k4 * 4 + 1) * 64);
        const float4* w2 = (const float4*)(Wp + (k4 * 4 + 2) * 64);
        const float4* w3 = (const float4*)(Wp + (k4 * 4 + 3) * 64);
#pragma unroll
        for (int q = 0; q < 16; ++q) {
            float4 v0 = w0[q], v1 = w1[q], v2 = w2[q], v3 = w3[q];
            a[q].x += iv.x * v0.x + iv.y * v1.x + iv.z * v2.x + iv.w * v3.x;
            a[q].y += iv.x * v0.y + iv.y * v1.y + iv.z * v2.y + iv.w * v3.y;
            a[q].z += iv.x * v0.z + iv.y * v1.z + iv.z * v2.z + iv.w * v3.z;
            a[q].w += iv.x * v0.w + iv.y * v1.w + iv.z * v2.w + iv.w * v3.w;
        }
    }
}

// g_new = cat(g|leaky, h[src], aggsink) @ W(192x64) + b   (stored PRE-leaky)
__global__ __launch_bounds__(256) void k_conv_net(
    float* __restrict__ g, const float* __restrict__ h, const float* __restrict__ aggsink,
    const int* __restrict__ src_nodes, const float* __restrict__ W, const float* __restrict__ b,
    int apply_leaky_g)
{
    int nid = blockIdx.x * 256 + threadIdx.x;
    int n = min(nid, N_NETS - 1);

    float4 a[16];
    const float4* bp = (const float4*)b;
#pragma unroll
    for (int q = 0; q < 16; ++q) a[q] = bp[q];

    float4 in[16];
    const float4* rp = (const float4*)(g + (size_t)n * 64);
#pragma unroll
    for (int q = 0; q < 16; ++q) in[q] = rp[q];
    if (apply_leaky_g) {
#pragma unroll
        for (int q = 0; q < 16; ++q) in[q] = leaky4(in[q]);
    }
    acc_part(a, in, W);

    int s = src_nodes[n];
    rp = (const float4*)(h + (size_t)s * 64);
#pragma unroll
    for (int q = 0; q < 16; ++q) in[q] = rp[q];
    acc_part(a, in, W + 64 * 64);

    rp = (const float4*)(aggsink + (size_t)n * 64);
#pragma unroll
    for (int q = 0; q < 16; ++q) in[q] = rp[q];
    acc_part(a, in, W + 128 * 64);

    if (nid < N_NETS) {
        float4* gp = (float4*)(g + (size_t)nid * 64);
#pragma unroll
        for (int q = 0; q < 16; ++q) gp[q] = a[q];
    }
}

// h_new = leaky( cat(h, back) @ W(128x64) + b )
__global__ __launch_bounds__(256) void k_conv_node(
    float* __restrict__ h, const float* __restrict__ back,
    const float* __restrict__ W, const float* __restrict__ b)
{
    int nid = blockIdx.x * 256 + threadIdx.x;
    int n = min(nid, N_NODES - 1);

    float4 a[16];
    const float4* bp = (const float4*)b;
#pragma unroll
    for (int q = 0; q < 16; ++q) a[q] = bp[q];

    float4 in[16];
    const float4* rp = (const float4*)(h + (size_t)n * 64);
#pragma unroll
    for (int q = 0; q < 16; ++q) in[q] = rp[q];
    acc_part(a, in, W);

    rp = (const float4*)(back + (size_t)n * 64);
#pragma unroll
    for (int q = 0; q < 16; ++q) in[q] = rp[q];
    acc_part(a, in, W + 64 * 64);

    if (nid < N_NODES) {
        float4* hp = (float4*)(h + (size_t)nid * 64);
#pragma unroll
        for (int q = 0; q < 16; ++q) hp[q] = leaky4(a[q]);
    }
}

// ================= virtual-node MLP (tiny: 1000 rows) =================
__global__ __launch_bounds__(256) void k_vn_update(
    float* __restrict__ vn, const unsigned* __restrict__ pooled,
    const float* __restrict__ W1, const float* __restrict__ b1,
    const float* __restrict__ W2, const float* __restrict__ b2)
{
    int wv = threadIdx.x >> 6, lane = threadIdx.x & 63;
    int v = blockIdx.x * 4 + wv;
    if (v >= NUM_VN) return;
    float p = dec(pooled[v * 64 + lane]);
    float vv = vn[v * 64 + lane];
    float tmp = p + vv;
    float t1 = b1[lane];
#pragma unroll 16
    for (int k = 0; k < 64; ++k) t1 += __shfl(tmp, k, 64) * W1[k * 64 + lane];
    t1 = leaky(t1);
    float t2 = b2[lane];
#pragma unroll 16
    for (int k = 0; k < 64; ++k) t2 += __shfl(t1, k, 64) * W2[k * 64 + lane];
    vn[v * 64 + lane] = vv + t2;
}

// ================= output heads (thread-per-row, scalar weight loads) =======

// node: 64 -> 256 (leaky) -> 4, abs
__global__ __launch_bounds__(256) void k_fc_node(
    float* __restrict__ out, const float* __restrict__ h,
    const float* __restrict__ W1t, const float* __restrict__ b1,
    const float* __restrict__ W2, const float* __restrict__ b2)
{
    int nid = blockIdx.x * 256 + threadIdx.x;
    int n = min(nid, N_NODES - 1);

    float4 hr[16];
    const float4* hp = (const float4*)(h + (size_t)n * 64);
#pragma unroll
    for (int q = 0; q < 16; ++q) hr[q] = hp[q];

    float po0 = 0.f, po1 = 0.f, po2 = 0.f, po3 = 0.f;
#pragma unroll 1
    for (int r = 0; r < 256; ++r) {
        const float4* wr = (const float4*)(W1t + r * 64);
        float p0 = 0.f, p1 = 0.f, p2 = 0.f, p3 = 0.f;
#pragma unroll
        for (int q = 0; q < 16; ++q) {
            float4 v = wr[q];
            p0 += hr[q].x * v.x; p1 += hr[q].y * v.y;
            p2 += hr[q].z * v.z; p3 += hr[q].w * v.w;
        }
        float act = leaky(b1[r] + ((p0 + p1) + (p2 + p3)));
        const float4* w2 = (const float4*)(W2 + r * 4);
        float4 v2 = w2[0];
        po0 += act * v2.x; po1 += act * v2.y; po2 += act * v2.z; po3 += act * v2.w;
    }
    if (nid < N_NODES) {
        float4 ov = make_float4(fabsf(po0 + b2[0]), fabsf(po1 + b2[1]),
                                fabsf(po2 + b2[2]), fabsf(po3 + b2[3]));
        *((float4*)(out + (size_t)nid * 4)) = ov;
    }
}

// net: 64 -> 64 (leaky) -> 4, abs   (input g stored pre-leaky)
__global__ __launch_bounds__(256) void k_fc_net(
    float* __restrict__ out, const float* __restrict__ g,
    const float* __restrict__ W1t, const float* __restrict__ b1,
    const float* __restrict__ W2, const float* __restrict__ b2)
{
    int nid = blockIdx.x * 256 + threadIdx.x;
    int n = min(nid, N_NETS - 1);

    float4 gr[16];
    const float4* gp = (const float4*)(g + (size_t)n * 64);
#pragma unroll
    for (int q = 0; q < 16; ++q) gr[q] = leaky4(gp[q]);

    float po0 = 0.f, po1 = 0.f, po2 = 0.f, po3 = 0.f;
#pragma unroll 1
    for (int r = 0; r < 64; ++r) {
        const float4* wr = (const float4*)(W1t + r * 64);
        float p0 = 0.f, p1 = 0.f, p2 = 0.f, p3 = 0.f;
#pragma unroll
        for (int q = 0; q < 16; ++q) {
            float4 v = wr[q];
            p0 += gr[q].x * v.x; p1 += gr[q].y * v.y;
            p2 += gr[q].z * v.z; p3 += gr[q].w * v.w;
        }
        float act = leaky(b1[r] + ((p0 + p1) + (p2 + p3)));
        const float4* w2 = (const float4*)(W2 + r * 4);
        float4 v2 = w2[0];
        po0 += act * v2.x; po1 += act * v2.y; po2 += act * v2.z; po3 += act * v2.w;
    }
    if (nid < N_NETS) {
        float4 ov = make_float4(fabsf(po0 + b2[0]), fabsf(po1 + b2[1]),
                                fabsf(po2 + b2[2]), fabsf(po3 + b2[3]));
        *((float4*)(out + (size_t)nid * 4)) = ov;
    }
}

extern "C" void kernel_launch(void* const* d_in, const int* in_sizes, int n_in,
                              void* d_out, int out_size, void* d_ws, size_t ws_size,
                              hipStream_t stream)
{
    const float* node_features = (const float*)d_in[0];
    const float* net_features  = (const float*)d_in[1];
    const int*   src_nodes     = (const int*)d_in[2];
    const int*   sink_nodes    = (const int*)d_in[3];
    const int*   sink_nets     = (const int*)d_in[4];
    const float* edge_weight   = (const float*)d_in[5];
    const int*   batch         = (const int*)d_in[6];
    const float* ne_W1 = (const float*)d_in[7];
    const float* ne_b1 = (const float*)d_in[8];
    const float* ne_W2 = (const float*)d_in[9];
    const float* ne_b2 = (const float*)d_in[10];
    const float* te_W1 = (const float*)d_in[11];
    const float* te_b1 = (const float*)d_in[12];
    const float* te_W2 = (const float*)d_in[13];
    const float* te_b2 = (const float*)d_in[14];
    const float* vn_emb = (const float*)d_in[15];
    const float* conv_Wnet  = (const float*)d_in[16];
    const float* conv_bnet  = (const float*)d_in[17];
    const float* conv_Wnode = (const float*)d_in[18];
    const float* conv_bnode = (const float*)d_in[19];
    const float* vn_W1 = (const float*)d_in[20];
    const float* vn_b1 = (const float*)d_in[21];
    const float* vn_W2 = (const float*)d_in[22];
    const float* vn_b2 = (const float*)d_in[23];
    const float* fc1n_W = (const float*)d_in[24];
    const float* fc1n_b = (const float*)d_in[25];
    const float* fc2n_W = (const float*)d_in[26];
    const float* fc2n_b = (const float*)d_in[27];
    const float* fc1e_W = (const float*)d_in[28];
    const float* fc1e_b = (const float*)d_in[29];
    const float* fc2e_W = (const float*)d_in[30];
    const float* fc2e_b = (const float*)d_in[31];

    float* out_node = (float*)d_out;
    float* out_net  = out_node + (size_t)N_NODES * 4;

    float* h       = (float*)d_ws;                       // N_NODES*64
    float* g       = h + (size_t)N_NODES * EMB;          // N_NETS*64
    float* scratch = g + (size_t)N_NETS * EMB;           // N_NODES*64 (aggsink/back/wT)
    float* vn      = scratch + (size_t)N_NODES * EMB;    // NUM_VN*64
    unsigned* pooled = (unsigned*)(vn + (size_t)NUM_VN * EMB);  // NUM_VN*64

    // transposed weights live at the head of scratch (re-built after conv loop)
    float* ne_W1t  = scratch;            // 4096
    float* te_W1t  = scratch + 4096;     // 1024
    float* fc1n_Wt = scratch + 5120;     // 16384
    float* fc1e_Wt = scratch + 21504;    // 4096

    const int nodeRowBlocks = (N_NODES + 255) / 256;
    const int netRowBlocks  = (N_NETS + 255) / 256;
    const int nodeWaveBlocks = (N_NODES + 3) / 4;
    const int netWaveBlocks  = (N_NETS + 3) / 4;
    const int edgeBlocks = (E_SINK + 3) / 4;
    const int vnBlocks   = (NUM_VN + 3) / 4;
    const int vnElemBlocks   = (NUM_VN * EMB + 255) / 256;
    const int nodeVec4Blocks = (N_NODES * 16 + 255) / 256;
    const int prepBlocks = (25600 + 255) / 256;

    k_prep_wt<<<prepBlocks, 256, 0, stream>>>(ne_W1, te_W1, fc1n_W, fc1e_W, scratch);
    k_node_enc<<<nodeRowBlocks, 256, 0, stream>>>(node_features, ne_W1t, ne_b1, ne_W2, ne_b2, h);
    k_net_enc<<<netRowBlocks, 256, 0, stream>>>(net_features, te_W1t, te_b1, te_W2, te_b2, g);
    k_vn_init<<<vnElemBlocks, 256, 0, stream>>>(vn, vn_emb);

    for (int l = 0; l < 3; ++l) {
        k_add_vn<<<nodeVec4Blocks, 256, 0, stream>>>((float4*)h, vn, batch);

        hipMemsetAsync(scratch, 0, (size_t)N_NETS * EMB * sizeof(float), stream);
        k_scatter_sink<<<edgeBlocks, 256, 0, stream>>>(scratch, h, sink_nodes, sink_nets, edge_weight);
        k_conv_net<<<netRowBlocks, 256, 0, stream>>>(g, h, scratch, src_nodes,
                                                     conv_Wnet + (size_t)l * 192 * 64,
                                                     conv_bnet + (size_t)l * 64, l > 0 ? 1 : 0);

        hipMemsetAsync(scratch, 0, (size_t)N_NODES * EMB * sizeof(float), stream);
        k_scatter_back_src<<<netWaveBlocks, 256, 0, stream>>>(scratch, g, src_nodes);
        k_scatter_back_sink<<<edgeBlocks, 256, 0, stream>>>(scratch, g, sink_nets, sink_nodes, edge_weight);
        k_conv_node<<<nodeRowBlocks, 256, 0, stream>>>(h, scratch,
                                                       conv_Wnode + (size_t)l * 128 * 64,
                                                       conv_bnode + (size_t)l * 64);

        if (l < 2) {
            k_pool_init<<<vnElemBlocks, 256, 0, stream>>>(pooled);
            k_pool_scatter<<<nodeWaveBlocks, 256, 0, stream>>>(pooled, h, batch);
            k_vn_update<<<vnBlocks, 256, 0, stream>>>(vn, pooled,
                                                      vn_W1 + (size_t)l * 64 * 64,
                                                      vn_b1 + (size_t)l * 64,
                                                      vn_W2 + (size_t)l * 64 * 64,
                                                      vn_b2 + (size_t)l * 64);
        }
    }

    // scratch was clobbered by the conv loop — rebuild transposed fc weights
    k_prep_wt<<<prepBlocks, 256, 0, stream>>>(ne_W1, te_W1, fc1n_W, fc1e_W, scratch);
    k_fc_node<<<nodeRowBlocks, 256, 0, stream>>>(out_node, h, fc1n_Wt, fc1n_b, fc2n_W, fc2n_b);
    k_fc_net<<<netRowBlocks, 256, 0, stream>>>(out_net, g, fc1e_Wt, fc1e_b, fc2e_W, fc2e_b);
}

// Round 4
// 2583.814 us; speedup vs baseline: 1.3768x; 1.3768x over previous
//
#include <hip/hip_runtime.h>
#include <cstdint>

static constexpr int N_NODES = 300000;
static constexpr int N_NETS  = 200000;
static constexpr int E_SINK  = 1000000;
static constexpr int NODE_DIM = 32;
static constexpr int NET_DIM  = 16;
static constexpr int EMB = 64;
static constexpr int NUM_VN = 1000;
#define SLOPE 0.01f

typedef __attribute__((ext_vector_type(8))) short bhalf8;
typedef __attribute__((ext_vector_type(4))) float floatx4;

__device__ __forceinline__ float leaky(float x) { return x >= 0.f ? x : SLOPE * x; }

// order-preserving f32 -> u32 encoding for atomicMax
__device__ __forceinline__ unsigned enc(float x) {
    unsigned u = __float_as_uint(x);
    return (u & 0x80000000u) ? ~u : (u | 0x80000000u);
}
__device__ __forceinline__ float dec(unsigned e) {
    unsigned u = (e & 0x80000000u) ? (e ^ 0x80000000u) : ~e;
    return __uint_as_float(u);
}

// ---------- bf16 split helpers ----------
__device__ __forceinline__ unsigned bf16_rne(float x) {
    unsigned u = __float_as_uint(x);
    return (u + 0x7FFFu + ((u >> 16) & 1u)) >> 16;
}
__device__ __forceinline__ void split8(const float* x, bhalf8& ah, bhalf8& al) {
#pragma unroll
    for (int e = 0; e < 8; ++e) {
        unsigned h = bf16_rne(x[e]);
        float fh = __uint_as_float(h << 16);
        unsigned l = bf16_rne(x[e] - fh);
        ah[e] = (short)h; al[e] = (short)l;
    }
}

// A-fragment from global f32 row (8 consecutive k), optional leaky
template<bool LK>
__device__ __forceinline__ void afrag_g(const float* rowp, int kbase, bhalf8& ah, bhalf8& al) {
    float4 v0 = *(const float4*)(rowp + kbase);
    float4 v1 = *(const float4*)(rowp + kbase + 4);
    float x[8] = {v0.x, v0.y, v0.z, v0.w, v1.x, v1.y, v1.z, v1.w};
    if (LK) {
#pragma unroll
        for (int e = 0; e < 8; ++e) x[e] = leaky(x[e]);
    }
    split8(x, ah, al);
}

// A-fragment from LDS f32 tile
__device__ __forceinline__ void afrag_l(const float* tp, bhalf8& ah, bhalf8& al) {
    float4 v0 = *(const float4*)tp;
    float4 v1 = *(const float4*)(tp + 4);
    float x[8] = {v0.x, v0.y, v0.z, v0.w, v1.x, v1.y, v1.z, v1.w};
    split8(x, ah, al);
}

// W-fragment: B operand, col fixed per lane, k = kt*32 + g*8 + e
__device__ __forceinline__ void wfrag(const float* W, int cols, int K, int col, bool colok,
                                      int kt, int g, bhalf8& wh, bhalf8& wl) {
    float x[8];
#pragma unroll
    for (int e = 0; e < 8; ++e) {
        int k = kt * 32 + g * 8 + e;
        x[e] = (k < K && colok) ? W[(size_t)k * cols + col] : 0.f;
    }
    split8(x, wh, wl);
}

__device__ __forceinline__ floatx4 mm3(bhalf8 ah, bhalf8 al, bhalf8 wh, bhalf8 wl, floatx4 c) {
    c = __builtin_amdgcn_mfma_f32_16x16x32_bf16(ah, wh, c, 0, 0, 0);
    c = __builtin_amdgcn_mfma_f32_16x16x32_bf16(ah, wl, c, 0, 0, 0);
    c = __builtin_amdgcn_mfma_f32_16x16x32_bf16(al, wh, c, 0, 0, 0);
    return c;
}

// ================= fused node encoder: 32 -> 128 (leaky) -> 64 =================
__global__ __launch_bounds__(256) void k_node_enc_mfma(
    const float* __restrict__ x, const float* __restrict__ W1, const float* __restrict__ b1,
    const float* __restrict__ W2, const float* __restrict__ b2, float* __restrict__ h)
{
    __shared__ __align__(16) float t[64][132];  // H=128, stride 132
    int lane = threadIdx.x & 63, wid = threadIdx.x >> 6;
    int g16 = lane >> 4, l15 = lane & 15;
    int rbase = blockIdx.x * 64;

    bhalf8 W1H[2], W1L[2];
#pragma unroll
    for (int s = 0; s < 2; ++s)
        wfrag(W1, 128, 32, wid * 16 + s * 64 + l15, true, 0, g16, W1H[s], W1L[s]);
    bhalf8 W2H[4], W2L[4];
#pragma unroll
    for (int kt = 0; kt < 4; ++kt)
        wfrag(W2, 64, 128, wid * 16 + l15, true, kt, g16, W2H[kt], W2L[kt]);

#pragma unroll
    for (int ms = 0; ms < 4; ++ms) {
        int r = min(rbase + ms * 16 + l15, N_NODES - 1);
        bhalf8 ah, al;
        afrag_g<false>(x + (size_t)r * NODE_DIM, g16 * 8, ah, al);
#pragma unroll
        for (int s = 0; s < 2; ++s) {
            floatx4 acc = {0.f, 0.f, 0.f, 0.f};
            acc = mm3(ah, al, W1H[s], W1L[s], acc);
            int hc = wid * 16 + s * 64 + l15;
            float bb = b1[hc];
#pragma unroll
            for (int i = 0; i < 4; ++i)
                t[ms * 16 + g16 * 4 + i][hc] = leaky(acc[i] + bb);
        }
    }
    __syncthreads();

    int cs = wid * 16 + l15;
    float bias = b2[cs];
#pragma unroll
    for (int ms = 0; ms < 4; ++ms) {
        floatx4 acc = {0.f, 0.f, 0.f, 0.f};
#pragma unroll
        for (int kt = 0; kt < 4; ++kt) {
            bhalf8 ah, al;
            afrag_l(&t[ms * 16 + l15][kt * 32 + g16 * 8], ah, al);
            acc = mm3(ah, al, W2H[kt], W2L[kt], acc);
        }
#pragma unroll
        for (int i = 0; i < 4; ++i) {
            int r = rbase + ms * 16 + g16 * 4 + i;
            if (r < N_NODES) h[(size_t)r * 64 + cs] = acc[i] + bias;
        }
    }
}

// ================= fused net encoder: 16 -> 64 (leaky) -> 64 =================
__global__ __launch_bounds__(256) void k_net_enc_mfma(
    const float* __restrict__ x, const float* __restrict__ W1, const float* __restrict__ b1,
    const float* __restrict__ W2, const float* __restrict__ b2, float* __restrict__ g)
{
    __shared__ __align__(16) float t[64][68];
    int lane = threadIdx.x & 63, wid = threadIdx.x >> 6;
    int g16 = lane >> 4, l15 = lane & 15;
    int rbase = blockIdx.x * 64;
    int cs = wid * 16 + l15;

    bhalf8 W1H, W1L;
    wfrag(W1, 64, 16, cs, true, 0, g16, W1H, W1L);
    bhalf8 W2H[2], W2L[2];
#pragma unroll
    for (int kt = 0; kt < 2; ++kt)
        wfrag(W2, 64, 64, cs, true, kt, g16, W2H[kt], W2L[kt]);

#pragma unroll
    for (int ms = 0; ms < 4; ++ms) {
        int r = min(rbase + ms * 16 + l15, N_NETS - 1);
        bhalf8 ah = {0,0,0,0,0,0,0,0}, al = {0,0,0,0,0,0,0,0};
        if (g16 < 2) afrag_g<false>(x + (size_t)r * NET_DIM, g16 * 8, ah, al);
        floatx4 acc = {0.f, 0.f, 0.f, 0.f};
        acc = mm3(ah, al, W1H, W1L, acc);
        float bb = b1[cs];
#pragma unroll
        for (int i = 0; i < 4; ++i)
            t[ms * 16 + g16 * 4 + i][cs] = leaky(acc[i] + bb);
    }
    __syncthreads();

    float bias = b2[cs];
#pragma unroll
    for (int ms = 0; ms < 4; ++ms) {
        floatx4 acc = {0.f, 0.f, 0.f, 0.f};
#pragma unroll
        for (int kt = 0; kt < 2; ++kt) {
            bhalf8 ah, al;
            afrag_l(&t[ms * 16 + l15][kt * 32 + g16 * 8], ah, al);
            acc = mm3(ah, al, W2H[kt], W2L[kt], acc);
        }
#pragma unroll
        for (int i = 0; i < 4; ++i) {
            int r = rbase + ms * 16 + g16 * 4 + i;
            if (r < N_NETS) g[(size_t)r * 64 + cs] = acc[i] + bias;
        }
    }
}

// ========== conv_net: g_new = cat(g|leaky, h[src], aggsink) @ W(192x64) + b ==========
__global__ __launch_bounds__(256) void k_conv_net_mfma(
    float* __restrict__ g, const float* __restrict__ h, const float* __restrict__ agg,
    const int* __restrict__ src, const float* __restrict__ W, const float* __restrict__ b, int lk0)
{
    int lane = threadIdx.x & 63, wid = threadIdx.x >> 6;
    int g16 = lane >> 4, l15 = lane & 15;
    int rbase = blockIdx.x * 64;
    int cs = wid * 16 + l15;

    bhalf8 WH[6], WL[6];
#pragma unroll
    for (int kt = 0; kt < 6; ++kt) wfrag(W, 64, 192, cs, true, kt, g16, WH[kt], WL[kt]);

    // prefetch in-place seg0 (g) fragments for all m-subtiles, then barrier
    bhalf8 GH[4][2], GL[4][2];
#pragma unroll
    for (int ms = 0; ms < 4; ++ms) {
        int r = min(rbase + ms * 16 + l15, N_NETS - 1);
        const float* rp = g + (size_t)r * 64;
#pragma unroll
        for (int kt = 0; kt < 2; ++kt) {
            if (lk0) afrag_g<true>(rp, kt * 32 + g16 * 8, GH[ms][kt], GL[ms][kt]);
            else     afrag_g<false>(rp, kt * 32 + g16 * 8, GH[ms][kt], GL[ms][kt]);
        }
    }
    __syncthreads();

    float bias = b[cs];
#pragma unroll
    for (int ms = 0; ms < 4; ++ms) {
        floatx4 acc = {0.f, 0.f, 0.f, 0.f};
#pragma unroll
        for (int kt = 0; kt < 2; ++kt) acc = mm3(GH[ms][kt], GL[ms][kt], WH[kt], WL[kt], acc);
        int ar = min(rbase + ms * 16 + l15, N_NETS - 1);
        const float* hp = h + (size_t)src[ar] * 64;
#pragma unroll
        for (int kt = 0; kt < 2; ++kt) {
            bhalf8 ah, al;
            afrag_g<false>(hp, kt * 32 + g16 * 8, ah, al);
            acc = mm3(ah, al, WH[2 + kt], WL[2 + kt], acc);
        }
        const float* ap = agg + (size_t)ar * 64;
#pragma unroll
        for (int kt = 0; kt < 2; ++kt) {
            bhalf8 ah, al;
            afrag_g<false>(ap, kt * 32 + g16 * 8, ah, al);
            acc = mm3(ah, al, WH[4 + kt], WL[4 + kt], acc);
        }
#pragma unroll
        for (int i = 0; i < 4; ++i) {
            int r = rbase + ms * 16 + g16 * 4 + i;
            if (r < N_NETS) g[(size_t)r * 64 + cs] = acc[i] + bias;
        }
    }
}

// ========== conv_node: h_new = leaky( cat(h, back) @ W(128x64) + b ) ==========
__global__ __launch_bounds__(256) void k_conv_node_mfma(
    float* __restrict__ h, const float* __restrict__ back,
    const float* __restrict__ W, const float* __restrict__ b)
{
    int lane = threadIdx.x & 63, wid = threadIdx.x >> 6;
    int g16 = lane >> 4, l15 = lane & 15;
    int rbase = blockIdx.x * 64;
    int cs = wid * 16 + l15;

    bhalf8 WH[4], WL[4];
#pragma unroll
    for (int kt = 0; kt < 4; ++kt) wfrag(W, 64, 128, cs, true, kt, g16, WH[kt], WL[kt]);

    bhalf8 HH[4][2], HL[4][2];
#pragma unroll
    for (int ms = 0; ms < 4; ++ms) {
        int r = min(rbase + ms * 16 + l15, N_NODES - 1);
        const float* rp = h + (size_t)r * 64;
#pragma unroll
        for (int kt = 0; kt < 2; ++kt)
            afrag_g<false>(rp, kt * 32 + g16 * 8, HH[ms][kt], HL[ms][kt]);
    }
    __syncthreads();

    float bias = b[cs];
#pragma unroll
    for (int ms = 0; ms < 4; ++ms) {
        floatx4 acc = {0.f, 0.f, 0.f, 0.f};
#pragma unroll
        for (int kt = 0; kt < 2; ++kt) acc = mm3(HH[ms][kt], HL[ms][kt], WH[kt], WL[kt], acc);
        int ar = min(rbase + ms * 16 + l15, N_NODES - 1);
        const float* bp = back + (size_t)ar * 64;
#pragma unroll
        for (int kt = 0; kt < 2; ++kt) {
            bhalf8 ah, al;
            afrag_g<false>(bp, kt * 32 + g16 * 8, ah, al);
            acc = mm3(ah, al, WH[2 + kt], WL[2 + kt], acc);
        }
#pragma unroll
        for (int i = 0; i < 4; ++i) {
            int r = rbase + ms * 16 + g16 * 4 + i;
            if (r < N_NODES) h[(size_t)r * 64 + cs] = leaky(acc[i] + bias);
        }
    }
}

// ========== fc_node head: 64 -> 256 (leaky) -> 4, abs ==========
__global__ __launch_bounds__(256) void k_fc_node_mfma(
    float* __restrict__ out, const float* __restrict__ h,
    const float* __restrict__ W1, const float* __restrict__ b1,
    const float* __restrict__ W2, const float* __restrict__ b2)
{
    __shared__ __align__(16) float t[64][260];  // H=256, stride 260
    int lane = threadIdx.x & 63, wid = threadIdx.x >> 6;
    int g16 = lane >> 4, l15 = lane & 15;
    int rbase = blockIdx.x * 64;

    bhalf8 W1H[4][2], W1L[4][2];
#pragma unroll
    for (int s = 0; s < 4; ++s)
#pragma unroll
        for (int kt = 0; kt < 2; ++kt)
            wfrag(W1, 256, 64, wid * 16 + s * 64 + l15, true, kt, g16, W1H[s][kt], W1L[s][kt]);

#pragma unroll
    for (int ms = 0; ms < 4; ++ms) {
        int r = min(rbase + ms * 16 + l15, N_NODES - 1);
        bhalf8 ah[2], al[2];
#pragma unroll
        for (int kt = 0; kt < 2; ++kt)
            afrag_g<false>(h + (size_t)r * 64, kt * 32 + g16 * 8, ah[kt], al[kt]);
#pragma unroll
        for (int s = 0; s < 4; ++s) {
            floatx4 acc = {0.f, 0.f, 0.f, 0.f};
#pragma unroll
            for (int kt = 0; kt < 2; ++kt) acc = mm3(ah[kt], al[kt], W1H[s][kt], W1L[s][kt], acc);
            int hc = wid * 16 + s * 64 + l15;
            float bb = b1[hc];
#pragma unroll
            for (int i = 0; i < 4; ++i)
                t[ms * 16 + g16 * 4 + i][hc] = leaky(acc[i] + bb);
        }
    }
    __syncthreads();

    // L2: K=256 -> 4 cols; wave wid handles m-subtile wid
    bhalf8 W2H[8], W2L[8];
#pragma unroll
    for (int kt = 0; kt < 8; ++kt)
        wfrag(W2, 4, 256, l15, l15 < 4, kt, g16, W2H[kt], W2L[kt]);

    floatx4 acc = {0.f, 0.f, 0.f, 0.f};
#pragma unroll
    for (int kt = 0; kt < 8; ++kt) {
        bhalf8 ah, al;
        afrag_l(&t[wid * 16 + l15][kt * 32 + g16 * 8], ah, al);
        acc = mm3(ah, al, W2H[kt], W2L[kt], acc);
    }
    if (l15 < 4) {
        float bo = b2[l15];
#pragma unroll
        for (int i = 0; i < 4; ++i) {
            int r = rbase + wid * 16 + g16 * 4 + i;
            if (r < N_NODES) out[(size_t)r * 4 + l15] = fabsf(acc[i] + bo);
        }
    }
}

// ========== fc_net head: 64 -> 64 (leaky) -> 4, abs  (g stored pre-leaky) ==========
__global__ __launch_bounds__(256) void k_fc_net_mfma(
    float* __restrict__ out, const float* __restrict__ g,
    const float* __restrict__ W1, const float* __restrict__ b1,
    const float* __restrict__ W2, const float* __restrict__ b2)
{
    __shared__ __align__(16) float t[64][68];
    int lane = threadIdx.x & 63, wid = threadIdx.x >> 6;
    int g16 = lane >> 4, l15 = lane & 15;
    int rbase = blockIdx.x * 64;
    int cs = wid * 16 + l15;

    bhalf8 W1H[2], W1L[2];
#pragma unroll
    for (int kt = 0; kt < 2; ++kt) wfrag(W1, 64, 64, cs, true, kt, g16, W1H[kt], W1L[kt]);

#pragma unroll
    for (int ms = 0; ms < 4; ++ms) {
        int r = min(rbase + ms * 16 + l15, N_NETS - 1);
        floatx4 acc = {0.f, 0.f, 0.f, 0.f};
#pragma unroll
        for (int kt = 0; kt < 2; ++kt) {
            bhalf8 ah, al;
            afrag_g<true>(g + (size_t)r * 64, kt * 32 + g16 * 8, ah, al);  // leaky on load
            acc = mm3(ah, al, W1H[kt], W1L[kt], acc);
        }
        float bb = b1[cs];
#pragma unroll
        for (int i = 0; i < 4; ++i)
            t[ms * 16 + g16 * 4 + i][cs] = leaky(acc[i] + bb);
    }
    __syncthreads();

    bhalf8 W2H[2], W2L[2];
#pragma unroll
    for (int kt = 0; kt < 2; ++kt)
        wfrag(W2, 4, 64, l15, l15 < 4, kt, g16, W2H[kt], W2L[kt]);

    floatx4 acc = {0.f, 0.f, 0.f, 0.f};
#pragma unroll
    for (int kt = 0; kt < 2; ++kt) {
        bhalf8 ah, al;
        afrag_l(&t[wid * 16 + l15][kt * 32 + g16 * 8], ah, al);
        acc = mm3(ah, al, W2H[kt], W2L[kt], acc);
    }
    if (l15 < 4) {
        float bo = b2[l15];
#pragma unroll
        for (int i = 0; i < 4; ++i) {
            int r = rbase + wid * 16 + g16 * 4 + i;
            if (r < N_NETS) out[(size_t)r * 4 + l15] = fabsf(acc[i] + bo);
        }
    }
}

// ================= misc elementwise =================
__global__ void k_vn_init(float* __restrict__ vn, const float* __restrict__ vn_emb) {
    int idx = blockIdx.x * blockDim.x + threadIdx.x;
    if (idx < NUM_VN * EMB) vn[idx] = vn_emb[idx & 63];
}

__global__ void k_add_vn(float4* __restrict__ h4, const float* __restrict__ vn,
                         const int* __restrict__ batch) {
    int idx = blockIdx.x * blockDim.x + threadIdx.x;
    if (idx >= N_NODES * 16) return;
    int n = idx >> 4, c4 = idx & 15;
    const float4* vr = (const float4*)(vn + (size_t)batch[n] * 64);
    float4 hv = h4[idx], vv = vr[c4];
    h4[idx] = make_float4(hv.x + vv.x, hv.y + vv.y, hv.z + vv.z, hv.w + vv.w);
}

__global__ void k_pool_init(unsigned* __restrict__ pooled) {
    int idx = blockIdx.x * blockDim.x + threadIdx.x;
    if (idx < NUM_VN * EMB) pooled[idx] = enc(-__builtin_inff());
}

// ================= scatters (wave per edge/row) =================
__global__ __launch_bounds__(256) void k_scatter_sink(
    float* __restrict__ agg, const float* __restrict__ h,
    const int* __restrict__ sink_nodes, const int* __restrict__ sink_nets,
    const float* __restrict__ ew)
{
    int wv = threadIdx.x >> 6, lane = threadIdx.x & 63;
    int e = blockIdx.x * 4 + wv;
    if (e >= E_SINK) return;
    int sn = sink_nodes[e], tg = sink_nets[e];
    float wt = ew[e];
    atomicAdd(&agg[(size_t)tg * 64 + lane], h[(size_t)sn * 64 + lane] * wt);
}

__global__ __launch_bounds__(256) void k_scatter_back_src(
    float* __restrict__ back, const float* __restrict__ g, const int* __restrict__ src_nodes)
{
    int wv = threadIdx.x >> 6, lane = threadIdx.x & 63;
    int n = blockIdx.x * 4 + wv;
    if (n >= N_NETS) return;
    atomicAdd(&back[(size_t)src_nodes[n] * 64 + lane], g[(size_t)n * 64 + lane]);
}

__global__ __launch_bounds__(256) void k_scatter_back_sink(
    float* __restrict__ back, const float* __restrict__ g,
    const int* __restrict__ sink_nets, const int* __restrict__ sink_nodes,
    const float* __restrict__ ew)
{
    int wv = threadIdx.x >> 6, lane = threadIdx.x & 63;
    int e = blockIdx.x * 4 + wv;
    if (e >= E_SINK) return;
    int tg = sink_nets[e], dn = sink_nodes[e];
    float wt = ew[e];
    atomicAdd(&back[(size_t)dn * 64 + lane], g[(size_t)tg * 64 + lane] * wt);
}

__global__ __launch_bounds__(256) void k_pool_scatter(
    unsigned* __restrict__ pooled, const float* __restrict__ h, const int* __restrict__ batch)
{
    int wv = threadIdx.x >> 6, lane = threadIdx.x & 63;
    int n = blockIdx.x * 4 + wv;
    if (n >= N_NODES) return;
    atomicMax(&pooled[batch[n] * 64 + lane], enc(h[(size_t)n * 64 + lane]));
}

// ================= virtual-node MLP (tiny: 1000 rows) =================
__global__ __launch_bounds__(256) void k_vn_update(
    float* __restrict__ vn, const unsigned* __restrict__ pooled,
    const float* __restrict__ W1, const float* __restrict__ b1,
    const float* __restrict__ W2, const float* __restrict__ b2)
{
    int wv = threadIdx.x >> 6, lane = threadIdx.x & 63;
    int v = blockIdx.x * 4 + wv;
    if (v >= NUM_VN) return;
    float p = dec(pooled[v * 64 + lane]);
    float vv = vn[v * 64 + lane];
    float tmp = p + vv;
    float t1 = b1[lane];
#pragma unroll 16
    for (int k = 0; k < 64; ++k) t1 += __shfl(tmp, k, 64) * W1[k * 64 + lane];
    t1 = leaky(t1);
    float t2 = b2[lane];
#pragma unroll 16
    for (int k = 0; k < 64; ++k) t2 += __shfl(t1, k, 64) * W2[k * 64 + lane];
    vn[v * 64 + lane] = vv + t2;
}

extern "C" void kernel_launch(void* const* d_in, const int* in_sizes, int n_in,
                              void* d_out, int out_size, void* d_ws, size_t ws_size,
                              hipStream_t stream)
{
    const float* node_features = (const float*)d_in[0];
    const float* net_features  = (const float*)d_in[1];
    const int*   src_nodes     = (const int*)d_in[2];
    const int*   sink_nodes    = (const int*)d_in[3];
    const int*   sink_nets     = (const int*)d_in[4];
    const float* edge_weight   = (const float*)d_in[5];
    const int*   batch         = (const int*)d_in[6];
    const float* ne_W1 = (const float*)d_in[7];
    const float* ne_b1 = (const float*)d_in[8];
    const float* ne_W2 = (const float*)d_in[9];
    const float* ne_b2 = (const float*)d_in[10];
    const float* te_W1 = (const float*)d_in[11];
    const float* te_b1 = (const float*)d_in[12];
    const float* te_W2 = (const float*)d_in[13];
    const float* te_b2 = (const float*)d_in[14];
    const float* vn_emb = (const float*)d_in[15];
    const float* conv_Wnet  = (const float*)d_in[16];
    const float* conv_bnet  = (const float*)d_in[17];
    const float* conv_Wnode = (const float*)d_in[18];
    const float* conv_bnode = (const float*)d_in[19];
    const float* vn_W1 = (const float*)d_in[20];
    const float* vn_b1 = (const float*)d_in[21];
    const float* vn_W2 = (const float*)d_in[22];
    const float* vn_b2 = (const float*)d_in[23];
    const float* fc1n_W = (const float*)d_in[24];
    const float* fc1n_b = (const float*)d_in[25];
    const float* fc2n_W = (const float*)d_in[26];
    const float* fc2n_b = (const float*)d_in[27];
    const float* fc1e_W = (const float*)d_in[28];
    const float* fc1e_b = (const float*)d_in[29];
    const float* fc2e_W = (const float*)d_in[30];
    const float* fc2e_b = (const float*)d_in[31];

    float* out_node = (float*)d_out;
    float* out_net  = out_node + (size_t)N_NODES * 4;

    float* h       = (float*)d_ws;                       // N_NODES*64
    float* g       = h + (size_t)N_NODES * EMB;          // N_NETS*64
    float* scratch = g + (size_t)N_NETS * EMB;           // N_NODES*64 (aggsink/back)
    float* vn      = scratch + (size_t)N_NODES * EMB;    // NUM_VN*64
    unsigned* pooled = (unsigned*)(vn + (size_t)NUM_VN * EMB);  // NUM_VN*64

    const int nodeTiles = (N_NODES + 63) / 64;   // 4688
    const int netTiles  = (N_NETS + 63) / 64;    // 3125
    const int nodeWaveBlocks = (N_NODES + 3) / 4;
    const int netWaveBlocks  = (N_NETS + 3) / 4;
    const int edgeBlocks = (E_SINK + 3) / 4;
    const int vnBlocks   = (NUM_VN + 3) / 4;
    const int vnElemBlocks   = (NUM_VN * EMB + 255) / 256;
    const int nodeVec4Blocks = (N_NODES * 16 + 255) / 256;

    k_node_enc_mfma<<<nodeTiles, 256, 0, stream>>>(node_features, ne_W1, ne_b1, ne_W2, ne_b2, h);
    k_net_enc_mfma<<<netTiles, 256, 0, stream>>>(net_features, te_W1, te_b1, te_W2, te_b2, g);
    k_vn_init<<<vnElemBlocks, 256, 0, stream>>>(vn, vn_emb);

    for (int l = 0; l < 3; ++l) {
        k_add_vn<<<nodeVec4Blocks, 256, 0, stream>>>((float4*)h, vn, batch);

        hipMemsetAsync(scratch, 0, (size_t)N_NETS * EMB * sizeof(float), stream);
        k_scatter_sink<<<edgeBlocks, 256, 0, stream>>>(scratch, h, sink_nodes, sink_nets, edge_weight);
        k_conv_net_mfma<<<netTiles, 256, 0, stream>>>(g, h, scratch, src_nodes,
                                                      conv_Wnet + (size_t)l * 192 * 64,
                                                      conv_bnet + (size_t)l * 64, l > 0 ? 1 : 0);

        hipMemsetAsync(scratch, 0, (size_t)N_NODES * EMB * sizeof(float), stream);
        k_scatter_back_src<<<netWaveBlocks, 256, 0, stream>>>(scratch, g, src_nodes);
        k_scatter_back_sink<<<edgeBlocks, 256, 0, stream>>>(scratch, g, sink_nets, sink_nodes, edge_weight);
        k_conv_node_mfma<<<nodeTiles, 256, 0, stream>>>(h, scratch,
                                                        conv_Wnode + (size_t)l * 128 * 64,
                                                        conv_bnode + (size_t)l * 64);

        if (l < 2) {
            k_pool_init<<<vnElemBlocks, 256, 0, stream>>>(pooled);
            k_pool_scatter<<<nodeWaveBlocks, 256, 0, stream>>>(pooled, h, batch);
            k_vn_update<<<vnBlocks, 256, 0, stream>>>(vn, pooled,
                                                      vn_W1 + (size_t)l * 64 * 64,
                                                      vn_b1 + (size_t)l * 64,
                                                      vn_W2 + (size_t)l * 64 * 64,
                                                      vn_b2 + (size_t)l * 64);
        }
    }

    k_fc_node_mfma<<<nodeTiles, 256, 0, stream>>>(out_node, h, fc1n_W, fc1n_b, fc2n_W, fc2n_b);
    k_fc_net_mfma<<<netTiles, 256, 0, stream>>>(out_net, g, fc1e_W, fc1e_b, fc2e_W, fc2e_b);
}